// Round 2
// baseline (615.138 us; speedup 1.0000x reference)
//
#include <hip/hip_runtime.h>
#include <hip/hip_bf16.h>

// BahdanauAttention: B=32, S=2048, H=512, D2=1024
// R8 = R7 with the epilogue write-collision fixed:
//   R7 bug: waves wn=0/wn=1 (same wm) each hold a DIFFERENT 64-col half of the
//   jblk score sum; plain store to spart[jblk][rg] collided (atomicAdd in R6
//   had summed them). Fix: 16 partial planes indexed jblk*2+wn; k_softmax sums
//   16. Everything else from R7 kept: dbuf T14 async-split K-loop in k_score4
//   (1 barrier/K-step), atomic-free k_context partials + k_reduce.

typedef __attribute__((ext_vector_type(8))) short bf16x8;
typedef __attribute__((ext_vector_type(4))) float f32x4;

__device__ __forceinline__ unsigned pk_bf16(float x, float y) {
  union { __hip_bfloat162 h; unsigned u; } c;
  c.h = __float22bfloat162_rn(make_float2(x, y));
  return c.u;
}

__device__ __forceinline__ float fast_tanh(float x) {
  float e = __expf(2.0f * x);
  return 1.0f - 2.0f / (e + 1.0f);
}

// async global->LDS, 16B per lane; LDS dest = wave-uniform base + lane*16
typedef const __attribute__((address_space(1))) void* gas_t;
typedef __attribute__((address_space(3))) void* las_t;
__device__ __forceinline__ void ld_lds16(const void* g, void* l) {
  __builtin_amdgcn_global_load_lds((gas_t)g, (las_t)l, 16, 0, 0);
}

// ---- fused: blocks [0,1024): qW; [1024,2048): Ua fp32->bf16 ----
__global__ __launch_bounds__(256) void k_fused(const float* __restrict__ query,
                                               const float* __restrict__ Wa_w,
                                               const float* __restrict__ Wa_b,
                                               const float* __restrict__ Ua_b,
                                               const float4* __restrict__ ua,
                                               float* __restrict__ qW,
                                               uint2* __restrict__ ua16) {
  const int t = threadIdx.x;
  if (blockIdx.x >= 1024) {   // ---- Ua cvt: 262144 float4 ----
    size_t i = (size_t)(blockIdx.x - 1024) * 256 + t;
    float4 v = ua[i];
    uint2 o;
    o.x = pk_bf16(v.x, v.y);
    o.y = pk_bf16(v.z, v.w);
    ua16[i] = o;
    return;
  }
  // ---- qW[b][j] = q_cat[b]·Wa_w[j] + Wa_b[j] + Ua_b[j] ----
  const int jc = blockIdx.x >> 5, b = blockIdx.x & 31;
  __shared__ float4 qloc[256];
  {
    // q_cat = concat(query[b,1,:], query[b,3,:]); query is (B,4,512)
    const float* base = (t < 128) ? (query + b * 2048 + 512) : (query + b * 2048 + 1536 - 512);
    qloc[t] = *(const float4*)(base + t * 4);
  }
  __syncthreads();
  const int jl = t >> 3, ks = t & 7;
  const int j = jc * 32 + jl;
  const float* wrow = Wa_w + j * 1024;
  float s = 0.f;
  #pragma unroll
  for (int i = 0; i < 32; ++i) {
    float4 wv = *(const float4*)(wrow + i * 32 + ks * 4);
    float4 q4 = qloc[i * 8 + ks];
    s += wv.x * q4.x + wv.y * q4.y + wv.z * q4.z + wv.w * q4.w;
  }
  s += __shfl_xor(s, 1);
  s += __shfl_xor(s, 2);
  s += __shfl_xor(s, 4);
  if (ks == 0) qW[b * 1024 + j] = s + Wa_b[j] + Ua_b[j];
}

// ---- score: tanh(keys@Uab^T + qW)·Va -> 16 partial score planes ----
// 128x128 tile, BK=64, double-buffered LDS, 1 barrier per K-step.
// A: fp32 keys -> regs (issued EARLY) -> cvt_pk -> swizzled ds_write (LATE).
// B: global_load_lds DMA from Uab (bf16, L2-resident via XCD pin), issued EARLY.
// vmcnt FIFO: [8 A-loads][4 DMA] => waiting on ra == vmcnt(4): DMA stays in
// flight across cvt, drained only at the barrier.
__global__ __launch_bounds__(256) void k_score4(const float* __restrict__ keys,
                                                const unsigned short* __restrict__ Uab,
                                                const float* __restrict__ qW,
                                                const float* __restrict__ Va,
                                                float* __restrict__ spart) {
  __shared__ __align__(16) unsigned short As[2][128 * 64];  // 2x16 KB
  __shared__ __align__(16) unsigned short Bs[2][128 * 64];  // 2x16 KB
  const int h = blockIdx.x;
  const int x = h & 7, g = h >> 3;
  const int jblk = g & 7;                    // 0..7
  const int rblk = x + ((g >> 3) << 3);      // 0..511, rblk%8 == h&7 (XCD pin)
  const int t = threadIdx.x;
  const int lane = t & 63, w = t >> 6;
  const int wm = w >> 1, wn = w & 1;
  const int l15 = lane & 15, quad = lane >> 4;
  const int row0 = rblk * 128, j0 = jblk * 128;
  const int rb = l15 & 7;
  const int aoff = (wm * 64 + l15) * 64;
  const int boff = (wn * 64 + l15) * 64;

  f32x4 acc[4][4];
  #pragma unroll
  for (int i = 0; i < 4; i++)
    #pragma unroll
    for (int j = 0; j < 4; j++) acc[i][j] = (f32x4){0.f, 0.f, 0.f, 0.f};

  // A staging: thread t -> rows (t>>3)+{0,32,64,96}, 8-k slot (t&7)
  const int srow = t >> 3, sslot = t & 7;
  const float* gA = keys + (size_t)(row0 + srow) * 1024 + sslot * 8;
  const int laOff = srow * 64 + ((sslot ^ (srow & 7)) * 8);  // (srow+32p)&7==srow&7

  // B DMA: chunk = 1KB = 8 rows x 128B; wave w stages chunks w*4+i
  const int lr = lane >> 3;                  // row-in-chunk 0..7
  const int sg = (lane & 7) ^ lr;            // swizzled 16B slot
  const unsigned short* gB = Uab + (size_t)(j0 + (w * 4) * 8 + lr) * 1024 + sg * 8;

  float4 ra[4][2];
  // ---- prologue: stage k0=0 into buffer 0 ----
  #pragma unroll
  for (int p = 0; p < 4; ++p) {
    const float* gp = gA + (size_t)p * 32 * 1024;
    ra[p][0] = *(const float4*)gp;
    ra[p][1] = *(const float4*)(gp + 4);
  }
  #pragma unroll
  for (int i = 0; i < 4; ++i)
    ld_lds16(gB + (size_t)i * 8 * 1024, &Bs[0][(w * 4 + i) * 512]);
  #pragma unroll
  for (int p = 0; p < 4; ++p) {
    uint4 o;
    o.x = pk_bf16(ra[p][0].x, ra[p][0].y);
    o.y = pk_bf16(ra[p][0].z, ra[p][0].w);
    o.z = pk_bf16(ra[p][1].x, ra[p][1].y);
    o.w = pk_bf16(ra[p][1].z, ra[p][1].w);
    *(uint4*)(&As[0][laOff + p * 32 * 64]) = o;
  }
  __syncthreads();

  #pragma unroll 2
  for (int kt = 0; kt < 16; ++kt) {
    const int cur = kt & 1, nxt = cur ^ 1;
    // ---- phase 1: issue next-tile loads (A regs first, then B DMA) ----
    if (kt < 15) {
      const int k0 = (kt + 1) * 64;
      #pragma unroll
      for (int p = 0; p < 4; ++p) {
        const float* gp = gA + (size_t)p * 32 * 1024 + k0;
        ra[p][0] = *(const float4*)gp;
        ra[p][1] = *(const float4*)(gp + 4);
      }
      __builtin_amdgcn_sched_barrier(0);   // keep A-loads ahead of DMA (vmcnt FIFO)
      #pragma unroll
      for (int i = 0; i < 4; ++i)
        ld_lds16(gB + (size_t)i * 8 * 1024 + k0, &Bs[nxt][(w * 4 + i) * 512]);
    }
    __builtin_amdgcn_sched_barrier(0);     // loads issued before MFMA cluster
    // ---- phase 2: MFMA on current buffers ----
    const unsigned short* Ac = &As[cur][0];
    const unsigned short* Bc = &Bs[cur][0];
    #pragma unroll
    for (int ks = 0; ks < 2; ++ks) {
      const int xf = ((ks * 4 + quad) ^ rb) * 8;   // swizzled frag slot
      bf16x8 bfr0 = *(const bf16x8*)(Bc + boff + 0 * 1024 + xf);
      bf16x8 bfr1 = *(const bf16x8*)(Bc + boff + 1 * 1024 + xf);
      bf16x8 bfr2 = *(const bf16x8*)(Bc + boff + 2 * 1024 + xf);
      bf16x8 bfr3 = *(const bf16x8*)(Bc + boff + 3 * 1024 + xf);
      #pragma unroll
      for (int i = 0; i < 4; i++) {
        bf16x8 af = *(const bf16x8*)(Ac + aoff + i * 1024 + xf);
        acc[i][0] = __builtin_amdgcn_mfma_f32_16x16x32_bf16(af, bfr0, acc[i][0], 0, 0, 0);
        acc[i][1] = __builtin_amdgcn_mfma_f32_16x16x32_bf16(af, bfr1, acc[i][1], 0, 0, 0);
        acc[i][2] = __builtin_amdgcn_mfma_f32_16x16x32_bf16(af, bfr2, acc[i][2], 0, 0, 0);
        acc[i][3] = __builtin_amdgcn_mfma_f32_16x16x32_bf16(af, bfr3, acc[i][3], 0, 0, 0);
      }
    }
    __builtin_amdgcn_sched_barrier(0);     // cvt (vmcnt wait) stays below MFMA
    // ---- phase 3: cvt + swizzled write into next buffer ----
    if (kt < 15) {
      #pragma unroll
      for (int p = 0; p < 4; ++p) {
        uint4 o;
        o.x = pk_bf16(ra[p][0].x, ra[p][0].y);
        o.y = pk_bf16(ra[p][0].z, ra[p][0].w);
        o.z = pk_bf16(ra[p][1].x, ra[p][1].y);
        o.w = pk_bf16(ra[p][1].z, ra[p][1].w);
        *(uint4*)(&As[nxt][laOff + p * 32 * 64]) = o;
      }
    }
    __syncthreads();   // drains DMA (had full MFMA phase) + ds_writes
  }

  // epilogue: per-(jblk,wn) partial: sum over this wave's 64 j-columns only.
  // Plane index jblk*2+wn -> exactly ONE writer per (plane, row). (R7 bug fix)
  const int b = row0 >> 11;
  float va[4], qb[4];
  #pragma unroll
  for (int j = 0; j < 4; j++) {
    int jg = j0 + wn * 64 + j * 16 + l15;
    va[j] = Va[jg];
    qb[j] = qW[b * 1024 + jg];
  }
  float* sp = spart + (jblk * 2 + wn) * 65536;
  #pragma unroll
  for (int i = 0; i < 4; i++) {
    #pragma unroll
    for (int r = 0; r < 4; r++) {
      float s = 0.f;
      #pragma unroll
      for (int j = 0; j < 4; j++)
        s += va[j] * fast_tanh(acc[i][j][r] + qb[j]);
      s += __shfl_xor(s, 1);
      s += __shfl_xor(s, 2);
      s += __shfl_xor(s, 4);
      s += __shfl_xor(s, 8);
      if (l15 == 0) {
        int rg = row0 + wm * 64 + i * 16 + quad * 4 + r;   // C/D: row = quad*4+reg
        sp[rg] = s;    // plain store: one writer per (plane, row)
      }
    }
  }
}

// ---- softmax over S=2048 per batch; sums the 16 partial planes ----
__global__ __launch_bounds__(256) void k_softmax(const float* __restrict__ spart,
                                                 float* __restrict__ wout) {
  const int b = blockIdx.x, t = threadIdx.x;
  const int lane = t & 63, w = t >> 6;
  __shared__ float red[4];
  float v[8];
  float mx = -1e30f;
  #pragma unroll
  for (int i = 0; i < 8; i++) {
    float s = 0.f;
    #pragma unroll
    for (int jb = 0; jb < 16; jb++) s += spart[jb * 65536 + b * 2048 + i * 256 + t];
    v[i] = s;
    mx = fmaxf(mx, s);
  }
  #pragma unroll
  for (int off = 1; off < 64; off <<= 1) mx = fmaxf(mx, __shfl_xor(mx, off));
  if (lane == 0) red[w] = mx;
  __syncthreads();
  mx = fmaxf(fmaxf(red[0], red[1]), fmaxf(red[2], red[3]));
  float sum = 0.f;
  #pragma unroll
  for (int i = 0; i < 8; i++) {
    v[i] = __expf(v[i] - mx);
    sum += v[i];
  }
  #pragma unroll
  for (int off = 1; off < 64; off <<= 1) sum += __shfl_xor(sum, off);
  __syncthreads();
  if (lane == 0) red[w] = sum;
  __syncthreads();
  sum = red[0] + red[1] + red[2] + red[3];
  float inv = 1.0f / sum;
  #pragma unroll
  for (int i = 0; i < 8; i++) wout[b * 2048 + i * 256 + t] = v[i] * inv;
}

// ---- context partials: block (sc,b) handles 128 s, writes cpart (NO atomics) ----
__global__ __launch_bounds__(256) void k_context(const float* __restrict__ keys,
                                                 const float* __restrict__ wts,
                                                 float* __restrict__ cpart) {
  const int sc = blockIdx.x;   // 0..15 (128 s each)
  const int b  = blockIdx.y;   // 0..31
  const int t  = threadIdx.x;
  __shared__ float wl[128];
  if (t < 128) wl[t] = wts[b * 2048 + sc * 128 + t];
  __syncthreads();
  const float4* kp = (const float4*)(keys + ((size_t)(b * 2048 + sc * 128) << 10)) + t;
  float4 a = {0.f, 0.f, 0.f, 0.f};
  #pragma unroll 8
  for (int s = 0; s < 128; ++s) {
    float4 kv = kp[s * 256];
    float wv = wl[s];
    a.x += wv * kv.x; a.y += wv * kv.y; a.z += wv * kv.z; a.w += wv * kv.w;
  }
  *((float4*)(cpart + ((size_t)(sc * 32 + b) << 10)) + t) = a;
}

// ---- reduce 16 context partials -> ctx ----
__global__ __launch_bounds__(256) void k_reduce(const float* __restrict__ cpart,
                                                float* __restrict__ ctx) {
  const int b = blockIdx.x, t = threadIdx.x;
  float4 a = {0.f, 0.f, 0.f, 0.f};
  #pragma unroll
  for (int sc = 0; sc < 16; ++sc) {
    float4 v = *((const float4*)(cpart + ((size_t)(sc * 32 + b) << 10)) + t);
    a.x += v.x; a.y += v.y; a.z += v.z; a.w += v.w;
  }
  *((float4*)(ctx + b * 1024) + t) = a;
}

extern "C" void kernel_launch(void* const* d_in, const int* in_sizes, int n_in,
                              void* d_out, int out_size, void* d_ws, size_t ws_size,
                              hipStream_t stream) {
  const float* query = (const float*)d_in[0];
  const float* keys  = (const float*)d_in[1];
  const float* Wa_w  = (const float*)d_in[2];
  const float* Wa_b  = (const float*)d_in[3];
  const float* Ua_w  = (const float*)d_in[4];
  const float* Ua_b  = (const float*)d_in[5];
  const float* Va_w  = (const float*)d_in[6];
  // d_in[7] = Va_b: unused (softmax shift-invariance)

  // ws layout (~8.1 MB): qW[32768] f32 | Uab 1M bf16 | spart 16x65536 f32 |
  //                      cpart 16x32x1024 f32
  float* qW = (float*)d_ws;
  unsigned short* Uab = (unsigned short*)(qW + 32768);
  float* spart = (float*)(Uab + 1048576);
  float* cpart = spart + 16 * 65536;

  float* ctx = (float*)d_out;        // context: 32*1024
  float* wts = ctx + 32768;          // weights: 32*2048

  k_fused<<<2048, 256, 0, stream>>>(query, Wa_w, Wa_b, Ua_b, (const float4*)Ua_w,
                                    qW, (uint2*)Uab);
  k_score4<<<4096, 256, 0, stream>>>(keys, Uab, qW, Va_w, spart);
  k_softmax<<<32, 256, 0, stream>>>(spart, wts);
  k_context<<<dim3(16, 32), 256, 0, stream>>>(keys, wts, cpart);
  k_reduce<<<32, 256, 0, stream>>>(cpart, ctx);
}

// Round 3
// 550.692 us; speedup vs baseline: 1.1170x; 1.1170x over previous
//
#include <hip/hip_runtime.h>
#include <hip/hip_bf16.h>

// BahdanauAttention: B=32, S=2048, H=512, D2=1024
// R9: k_score4 = R6's single-buffer 32KB structure (occupancy preserved) +
//     register A-prefetch: next tile's 8 fp32 loads issue AFTER the
//     tiles-resident barrier, BEFORE the MFMA cluster -> HBM latency hides
//     under MFMA + next barrier. cvt+ds_write happen at top of next iter from
//     regs (vmcnt(4) already satisfied). R7's dbuf (64KB LDS) is reverted --
//     it cost occupancy (32.6->21.8%) and regressed 251->305us.
//     Kept from R8: 16-plane plain-store score epilogue, atomic-free
//     k_context+k_reduce. k_softmax plane-sum vectorized to float4.

typedef __attribute__((ext_vector_type(8))) short bf16x8;
typedef __attribute__((ext_vector_type(4))) float f32x4;

__device__ __forceinline__ unsigned pk_bf16(float x, float y) {
  union { __hip_bfloat162 h; unsigned u; } c;
  c.h = __float22bfloat162_rn(make_float2(x, y));
  return c.u;
}

__device__ __forceinline__ float fast_tanh(float x) {
  float e = __expf(2.0f * x);
  return 1.0f - 2.0f / (e + 1.0f);
}

// async global->LDS, 16B per lane; LDS dest = wave-uniform base + lane*16
typedef const __attribute__((address_space(1))) void* gas_t;
typedef __attribute__((address_space(3))) void* las_t;
__device__ __forceinline__ void ld_lds16(const void* g, void* l) {
  __builtin_amdgcn_global_load_lds((gas_t)g, (las_t)l, 16, 0, 0);
}

// ---- fused: blocks [0,1024): qW; [1024,2048): Ua fp32->bf16 ----
__global__ __launch_bounds__(256) void k_fused(const float* __restrict__ query,
                                               const float* __restrict__ Wa_w,
                                               const float* __restrict__ Wa_b,
                                               const float* __restrict__ Ua_b,
                                               const float4* __restrict__ ua,
                                               float* __restrict__ qW,
                                               uint2* __restrict__ ua16) {
  const int t = threadIdx.x;
  if (blockIdx.x >= 1024) {   // ---- Ua cvt: 262144 float4 ----
    size_t i = (size_t)(blockIdx.x - 1024) * 256 + t;
    float4 v = ua[i];
    uint2 o;
    o.x = pk_bf16(v.x, v.y);
    o.y = pk_bf16(v.z, v.w);
    ua16[i] = o;
    return;
  }
  // ---- qW[b][j] = q_cat[b]·Wa_w[j] + Wa_b[j] + Ua_b[j] ----
  const int jc = blockIdx.x >> 5, b = blockIdx.x & 31;
  __shared__ float4 qloc[256];
  {
    // q_cat = concat(query[b,1,:], query[b,3,:]); query is (B,4,512)
    const float* base = (t < 128) ? (query + b * 2048 + 512) : (query + b * 2048 + 1536 - 512);
    qloc[t] = *(const float4*)(base + t * 4);
  }
  __syncthreads();
  const int jl = t >> 3, ks = t & 7;
  const int j = jc * 32 + jl;
  const float* wrow = Wa_w + j * 1024;
  float s = 0.f;
  #pragma unroll
  for (int i = 0; i < 32; ++i) {
    float4 wv = *(const float4*)(wrow + i * 32 + ks * 4);
    float4 q4 = qloc[i * 8 + ks];
    s += wv.x * q4.x + wv.y * q4.y + wv.z * q4.z + wv.w * q4.w;
  }
  s += __shfl_xor(s, 1);
  s += __shfl_xor(s, 2);
  s += __shfl_xor(s, 4);
  if (ks == 0) qW[b * 1024 + j] = s + Wa_b[j] + Ua_b[j];
}

// ---- score: tanh(keys@Uab^T + qW)·Va -> 16 partial score planes ----
// 128x128 tile, BK=64, SINGLE-buffer LDS (32KB), 2 barriers/K-step, but the
// next tile's A fp32 loads are issued between barB and the MFMA cluster so
// their latency hides under MFMA + barA. vmcnt FIFO per iter:
// [8 A-loads (prev iter, pre-MFMA)][4 B-DMA (this iter)] -> cvt waits
// vmcnt(4) which is long satisfied; barB drains the DMA.
__global__ __launch_bounds__(256) void k_score4(const float* __restrict__ keys,
                                                const unsigned short* __restrict__ Uab,
                                                const float* __restrict__ qW,
                                                const float* __restrict__ Va,
                                                float* __restrict__ spart) {
  __shared__ __align__(16) unsigned short As[128 * 64];  // 16 KB
  __shared__ __align__(16) unsigned short Bs[128 * 64];  // 16 KB
  const int h = blockIdx.x;
  const int x = h & 7, g = h >> 3;
  const int jblk = g & 7;                    // 0..7
  const int rblk = x + ((g >> 3) << 3);      // 0..511, rblk%8 == h&7 (XCD pin)
  const int t = threadIdx.x;
  const int lane = t & 63, w = t >> 6;
  const int wm = w >> 1, wn = w & 1;
  const int l15 = lane & 15, quad = lane >> 4;
  const int row0 = rblk * 128, j0 = jblk * 128;
  const int rb = l15 & 7;
  const int aoff = (wm * 64 + l15) * 64;
  const int boff = (wn * 64 + l15) * 64;

  f32x4 acc[4][4];
  #pragma unroll
  for (int i = 0; i < 4; i++)
    #pragma unroll
    for (int j = 0; j < 4; j++) acc[i][j] = (f32x4){0.f, 0.f, 0.f, 0.f};

  // A staging: thread t -> rows (t>>3)+{0,32,64,96}, 8-k slot (t&7)
  const int srow = t >> 3, sslot = t & 7;
  const float* gA = keys + (size_t)(row0 + srow) * 1024 + sslot * 8;
  unsigned short* lA = As + srow * 64 + ((sslot ^ (srow & 7)) * 8);  // (srow+32p)&7==srow&7

  // B DMA: chunk = 1KB = 8 rows x 128B; wave w stages chunks w*4+i
  const int lr = lane >> 3;                  // row-in-chunk 0..7
  const int sg = (lane & 7) ^ lr;            // swizzled 16B slot
  const unsigned short* gB = Uab + (size_t)(j0 + (w * 4) * 8 + lr) * 1024 + sg * 8;

  // ---- prologue: issue A-loads for tile 0 ----
  float4 ra[4][2];
  #pragma unroll
  for (int p = 0; p < 4; ++p) {
    const float* gp = gA + (size_t)p * 32 * 1024;
    ra[p][0] = *(const float4*)gp;
    ra[p][1] = *(const float4*)(gp + 4);
  }

  for (int kt = 0; kt < 16; ++kt) {
    const int k0 = kt * 64;
    if (kt) __syncthreads();   // barA: prior MFMA readers of As/Bs done
    // ---- write phase: B DMA (tile kt) + cvt ra -> As (tile kt) ----
    #pragma unroll
    for (int i = 0; i < 4; ++i)
      ld_lds16(gB + (size_t)i * 8 * 1024 + k0, Bs + (w * 4 + i) * 512);
    #pragma unroll
    for (int p = 0; p < 4; ++p) {
      uint4 o;
      o.x = pk_bf16(ra[p][0].x, ra[p][0].y);
      o.y = pk_bf16(ra[p][0].z, ra[p][0].w);
      o.z = pk_bf16(ra[p][1].x, ra[p][1].y);
      o.w = pk_bf16(ra[p][1].z, ra[p][1].w);
      *(uint4*)(lA + p * 32 * 64) = o;
    }
    __syncthreads();           // barB: As writes + B DMA resident
    // ---- prefetch: issue next tile's A fp32 loads (latency hides under MFMA) ----
    if (kt < 15) {
      #pragma unroll
      for (int p = 0; p < 4; ++p) {
        const float* gp = gA + (size_t)p * 32 * 1024 + k0 + 64;
        ra[p][0] = *(const float4*)gp;
        ra[p][1] = *(const float4*)(gp + 4);
      }
    }
    __builtin_amdgcn_sched_barrier(0);   // keep load-issue above the MFMA cluster
    // ---- MFMA phase on current tiles ----
    #pragma unroll
    for (int ks = 0; ks < 2; ++ks) {
      const int xf = ((ks * 4 + quad) ^ rb) * 8;   // swizzled frag slot
      bf16x8 bfr0 = *(const bf16x8*)(Bs + boff + 0 * 1024 + xf);
      bf16x8 bfr1 = *(const bf16x8*)(Bs + boff + 1 * 1024 + xf);
      bf16x8 bfr2 = *(const bf16x8*)(Bs + boff + 2 * 1024 + xf);
      bf16x8 bfr3 = *(const bf16x8*)(Bs + boff + 3 * 1024 + xf);
      #pragma unroll
      for (int i = 0; i < 4; i++) {
        bf16x8 af = *(const bf16x8*)(As + aoff + i * 1024 + xf);
        acc[i][0] = __builtin_amdgcn_mfma_f32_16x16x32_bf16(af, bfr0, acc[i][0], 0, 0, 0);
        acc[i][1] = __builtin_amdgcn_mfma_f32_16x16x32_bf16(af, bfr1, acc[i][1], 0, 0, 0);
        acc[i][2] = __builtin_amdgcn_mfma_f32_16x16x32_bf16(af, bfr2, acc[i][2], 0, 0, 0);
        acc[i][3] = __builtin_amdgcn_mfma_f32_16x16x32_bf16(af, bfr3, acc[i][3], 0, 0, 0);
      }
    }
  }

  // epilogue: per-(jblk,wn) partial: sum over this wave's 64 j-columns only.
  // Plane index jblk*2+wn -> exactly ONE writer per (plane, row).
  const int b = row0 >> 11;
  float va[4], qb[4];
  #pragma unroll
  for (int j = 0; j < 4; j++) {
    int jg = j0 + wn * 64 + j * 16 + l15;
    va[j] = Va[jg];
    qb[j] = qW[b * 1024 + jg];
  }
  float* sp = spart + (jblk * 2 + wn) * 65536;
  #pragma unroll
  for (int i = 0; i < 4; i++) {
    #pragma unroll
    for (int r = 0; r < 4; r++) {
      float s = 0.f;
      #pragma unroll
      for (int j = 0; j < 4; j++)
        s += va[j] * fast_tanh(acc[i][j][r] + qb[j]);
      s += __shfl_xor(s, 1);
      s += __shfl_xor(s, 2);
      s += __shfl_xor(s, 4);
      s += __shfl_xor(s, 8);
      if (l15 == 0) {
        int rg = row0 + wm * 64 + i * 16 + quad * 4 + r;   // C/D: row = quad*4+reg
        sp[rg] = s;    // plain store: one writer per (plane, row)
      }
    }
  }
}

// ---- softmax over S=2048 per batch; sums the 16 partial planes (float4) ----
__global__ __launch_bounds__(256) void k_softmax(const float* __restrict__ spart,
                                                 float* __restrict__ wout) {
  const int b = blockIdx.x, t = threadIdx.x;
  const int lane = t & 63, w = t >> 6;
  __shared__ float red[4];
  // thread t owns elements [t*8, t*8+8)
  float4 a0 = {0.f, 0.f, 0.f, 0.f}, a1 = {0.f, 0.f, 0.f, 0.f};
  #pragma unroll
  for (int jb = 0; jb < 16; jb++) {
    const float* p = spart + jb * 65536 + b * 2048 + t * 8;
    float4 u0 = *(const float4*)p;
    float4 u1 = *(const float4*)(p + 4);
    a0.x += u0.x; a0.y += u0.y; a0.z += u0.z; a0.w += u0.w;
    a1.x += u1.x; a1.y += u1.y; a1.z += u1.z; a1.w += u1.w;
  }
  float v[8] = {a0.x, a0.y, a0.z, a0.w, a1.x, a1.y, a1.z, a1.w};
  float mx = -1e30f;
  #pragma unroll
  for (int i = 0; i < 8; i++) mx = fmaxf(mx, v[i]);
  #pragma unroll
  for (int off = 1; off < 64; off <<= 1) mx = fmaxf(mx, __shfl_xor(mx, off));
  if (lane == 0) red[w] = mx;
  __syncthreads();
  mx = fmaxf(fmaxf(red[0], red[1]), fmaxf(red[2], red[3]));
  float sum = 0.f;
  #pragma unroll
  for (int i = 0; i < 8; i++) {
    v[i] = __expf(v[i] - mx);
    sum += v[i];
  }
  #pragma unroll
  for (int off = 1; off < 64; off <<= 1) sum += __shfl_xor(sum, off);
  __syncthreads();
  if (lane == 0) red[w] = sum;
  __syncthreads();
  sum = red[0] + red[1] + red[2] + red[3];
  float inv = 1.0f / sum;
  float4 o0 = {v[0] * inv, v[1] * inv, v[2] * inv, v[3] * inv};
  float4 o1 = {v[4] * inv, v[5] * inv, v[6] * inv, v[7] * inv};
  *(float4*)(wout + b * 2048 + t * 8) = o0;
  *(float4*)(wout + b * 2048 + t * 8 + 4) = o1;
}

// ---- context partials: block (sc,b) handles 128 s, writes cpart (NO atomics) ----
__global__ __launch_bounds__(256) void k_context(const float* __restrict__ keys,
                                                 const float* __restrict__ wts,
                                                 float* __restrict__ cpart) {
  const int sc = blockIdx.x;   // 0..15 (128 s each)
  const int b  = blockIdx.y;   // 0..31
  const int t  = threadIdx.x;
  __shared__ float wl[128];
  if (t < 128) wl[t] = wts[b * 2048 + sc * 128 + t];
  __syncthreads();
  const float4* kp = (const float4*)(keys + ((size_t)(b * 2048 + sc * 128) << 10)) + t;
  float4 a = {0.f, 0.f, 0.f, 0.f};
  #pragma unroll 8
  for (int s = 0; s < 128; ++s) {
    float4 kv = kp[s * 256];
    float wv = wl[s];
    a.x += wv * kv.x; a.y += wv * kv.y; a.z += wv * kv.z; a.w += wv * kv.w;
  }
  *((float4*)(cpart + ((size_t)(sc * 32 + b) << 10)) + t) = a;
}

// ---- reduce 16 context partials -> ctx ----
__global__ __launch_bounds__(256) void k_reduce(const float* __restrict__ cpart,
                                                float* __restrict__ ctx) {
  const int b = blockIdx.x, t = threadIdx.x;
  float4 a = {0.f, 0.f, 0.f, 0.f};
  #pragma unroll
  for (int sc = 0; sc < 16; ++sc) {
    float4 v = *((const float4*)(cpart + ((size_t)(sc * 32 + b) << 10)) + t);
    a.x += v.x; a.y += v.y; a.z += v.z; a.w += v.w;
  }
  *((float4*)(ctx + b * 1024) + t) = a;
}

extern "C" void kernel_launch(void* const* d_in, const int* in_sizes, int n_in,
                              void* d_out, int out_size, void* d_ws, size_t ws_size,
                              hipStream_t stream) {
  const float* query = (const float*)d_in[0];
  const float* keys  = (const float*)d_in[1];
  const float* Wa_w  = (const float*)d_in[2];
  const float* Wa_b  = (const float*)d_in[3];
  const float* Ua_w  = (const float*)d_in[4];
  const float* Ua_b  = (const float*)d_in[5];
  const float* Va_w  = (const float*)d_in[6];
  // d_in[7] = Va_b: unused (softmax shift-invariance)

  // ws layout (~8.1 MB): qW[32768] f32 | Uab 1M bf16 | spart 16x65536 f32 |
  //                      cpart 16x32x1024 f32
  float* qW = (float*)d_ws;
  unsigned short* Uab = (unsigned short*)(qW + 32768);
  float* spart = (float*)(Uab + 1048576);
  float* cpart = spart + 16 * 65536;

  float* ctx = (float*)d_out;        // context: 32*1024
  float* wts = ctx + 32768;          // weights: 32*2048

  k_fused<<<2048, 256, 0, stream>>>(query, Wa_w, Wa_b, Ua_b, (const float4*)Ua_w,
                                    qW, (uint2*)Uab);
  k_score4<<<4096, 256, 0, stream>>>(keys, Uab, qW, Va_w, spart);
  k_softmax<<<32, 256, 0, stream>>>(spart, wts);
  k_context<<<dim3(16, 32), 256, 0, stream>>>(keys, wts, cpart);
  k_reduce<<<32, 256, 0, stream>>>(cpart, ctx);
}